// Round 1
// baseline (408.099 us; speedup 1.0000x reference)
//
#include <hip/hip_runtime.h>

// FieldAwareInteractionLayer: out[b,p,:] = table[X[b,i_p], j_p, :] * table[X[b,j_p], i_p, :]
// F=39 fields, 741 upper-triangular pairs, EMB=16 (4 x float4).
// Memory-bound gather-multiply-store. 1 thread per output float4.

#define F       39
#define EMBF4   4     // 16 floats = 4 float4
#define NPAIR   741   // 39*38/2
#define PPB     64    // pairs per 256-thread block

__global__ __launch_bounds__(256) void ffm_interact_kernel(
    const int* __restrict__ X,
    const float4* __restrict__ table4,   // [100000][39][4] float4
    float4* __restrict__ out4)           // [B][741][4]  float4
{
    __shared__ int xrow[F];
    const int b = blockIdx.y;
    if (threadIdx.x < F) xrow[threadIdx.x] = X[b * F + threadIdx.x];
    __syncthreads();

    const int lane_e = threadIdx.x & 3;                    // which float4 of embedding
    const int p = blockIdx.x * PPB + (threadIdx.x >> 2);   // pair index
    if (p >= NPAIR) return;

    // Decode p -> (i, j), i<j: p = start(i) + (j - i - 1), start(i) = i*(77-i)/2
    int i = (int)((77.0f - sqrtf(5929.0f - 8.0f * (float)p)) * 0.5f);
    i = i < 0 ? 0 : (i > 38 ? 38 : i);
    while (((i + 1) * (77 - (i + 1))) / 2 <= p) ++i;   // fixup (at most 1 step)
    while ((i * (77 - i)) / 2 > p) --i;
    const int j = p - (i * (77 - i)) / 2 + i + 1;

    const int ri = xrow[i];
    const int rj = xrow[j];

    const float4 L = table4[(ri * F + j) * EMBF4 + lane_e];
    const float4 R = table4[(rj * F + i) * EMBF4 + lane_e];

    float4 o;
    o.x = L.x * R.x;
    o.y = L.y * R.y;
    o.z = L.z * R.z;
    o.w = L.w * R.w;
    out4[(b * NPAIR + p) * EMBF4 + lane_e] = o;
}

extern "C" void kernel_launch(void* const* d_in, const int* in_sizes, int n_in,
                              void* d_out, int out_size, void* d_ws, size_t ws_size,
                              hipStream_t stream) {
    const int*   X     = (const int*)d_in[0];
    const float* table = (const float*)d_in[1];
    float*       out   = (float*)d_out;

    const int batch = in_sizes[0] / F;   // 4096

    dim3 grid((NPAIR + PPB - 1) / PPB, batch);   // (12, 4096)
    ffm_interact_kernel<<<grid, 256, 0, stream>>>(
        X, (const float4*)table, (float4*)out);
}